// Round 6
// baseline (103.119 us; speedup 1.0000x reference)
//
#include <hip/hip_runtime.h>
#include <math.h>

#define BB 4
#define SS 16384
#define NN 1024
#define DD 64
#define MW 32        // bitmap words per row = NN/32
#define KSEG 32      // segments per batch (512 flows each)
#define CAPSEG 12    // entries per (node,seg): Poisson(0.5) -> P(>=13) ~ 2e-14
#define NCAP 128     // neighbor-list cap: <=64 in-nbrs + <=64 out-nbrs

__device__ __forceinline__ float wave_sum(float v) {
    #pragma unroll
    for (int off = 32; off > 0; off >>= 1) v += __shfl_xor(v, off, 64);
    return v;
}
__device__ __forceinline__ float wave_max(float v) {
    #pragma unroll
    for (int off = 32; off > 0; off >>= 1) v = fmaxf(v, __shfl_xor(v, off, 64));
    return v;
}

// Kernel 1: segmented build, zero-init fused (LDS counters owned per block).
// Node-major buckets: row i's 32 segment slots are one contiguous region.
// Counts packed to u8 (cd | cs<<4, both clamped to 12 < 16): 128 KB total.
__global__ __launch_bounds__(512) void build_kernel(
        const int* __restrict__ src_ips, const int* __restrict__ dst_ips,
        unsigned char* __restrict__ cnt8, int* __restrict__ bkt_d,
        unsigned short* __restrict__ bkt_s) {
    __shared__ int cd[NN], cs_[NN];
    int t = threadIdx.x;
    cd[t] = 0; cd[t + 512] = 0; cs_[t] = 0; cs_[t + 512] = 0;
    __syncthreads();
    int b = blockIdx.x >> 5, seg = blockIdx.x & 31;
    int local = (seg << 9) + t;                 // flow id within batch, < 16384
    int f = (b << 14) + local;
    int src = src_ips[f], dst = dst_ips[f];
    int pd = atomicAdd(&cd[dst], 1);
    if (pd < CAPSEG)
        bkt_d[(size_t)(((b << 10) + dst) * KSEG + seg) * CAPSEG + pd]
            = local | (src << 16);
    int ps = atomicAdd(&cs_[src], 1);
    if (ps < CAPSEG)
        bkt_s[(size_t)(((b << 10) + src) * KSEG + seg) * CAPSEG + ps]
            = (unsigned short)dst;
    __syncthreads();
    int n0 = t, n1 = t + 512;
    cnt8[(size_t)((b << 10) + n0) * KSEG + seg]
        = (unsigned char)(min(cd[n0], CAPSEG) | (min(cs_[n0], CAPSEG) << 4));
    cnt8[(size_t)((b << 10) + n1) * KSEG + seg]
        = (unsigned char)(min(cd[n1], CAPSEG) | (min(cs_[n1], CAPSEG) << 4));
}

// Kernel 2: one wave per row, BARRIER-FREE (only same-wave LDS: hs + bm).
// 32-byte coalesced packed-count read; single packed prefix scan (d|s<<16);
// 32-iter assembly from node-major buckets into per-lane registers; pipelined
// float4 ff gather; normalize; h@W with W read directly (L2/L3-hot, coalesced
// 256 B per k — no 16 KB staging, no __syncthreads); f1/f2; neighbor bitmap ->
// compact ascending list for kernel 3.
__global__ __launch_bounds__(256) void gather_kernel(
        const float* __restrict__ ff, const unsigned char* __restrict__ cnt8,
        const int* __restrict__ bkt_d, const unsigned short* __restrict__ bkt_s,
        const float* __restrict__ W, const float* __restrict__ a1,
        const float* __restrict__ a2, float* __restrict__ Wh,
        float* __restrict__ f1, float* __restrict__ f2,
        int* __restrict__ nbr, int* __restrict__ cntn) {
    __shared__ float hs[4][DD];                 // 1 KB
    __shared__ unsigned int bm[4][MW];          // 512 B
    int t = threadIdx.x, wave = t >> 6, lane = t & 63;
    int row = blockIdx.x * 4 + wave;            // [0, BB*NN)
    int b = row >> 10;
    if (lane < MW) bm[wave][lane] = 0u;         // same-wave DS: ordered

    // packed per-seg counts: one coalesced 32 B read (lane s < 32)
    int cb = (lane < KSEG) ? (int)cnt8[(size_t)row * KSEG + lane] : 0;
    int cv = (cb & 15) | ((cb >> 4) << 16);     // d in low16, s in high16
    int x = cv;                                 // packed inclusive prefix scan
    #pragma unroll
    for (int off = 1; off < 64; off <<= 1) {
        int y = __shfl_up(x, off, 64);
        if (lane >= off) x += y;
    }
    int tot = __shfl(x, 63, 64);
    int c1 = tot & 0xFFFF, c2 = tot >> 16;      // totals (~16 each)
    int ex = x - cv;                            // packed exclusive offsets
    int bkreg = 0, dreg = -1;                   // slot `lane` entries
    size_t rowB = (size_t)row * (KSEG * CAPSEG);
    for (int s = 0; s < KSEG; ++s) {
        int cvs = __shfl(cv, s, 64);
        int exs = __shfl(ex, s, 64);
        int csd = cvs & 0xFFFF, bd = exs & 0xFFFF;
        int css = cvs >> 16,    bs = exs >> 16;
        if (lane >= bd && lane < bd + csd)
            bkreg = bkt_d[rowB + s * CAPSEG + (lane - bd)];
        if (lane >= bs && lane < bs + css)
            dreg = bkt_s[rowB + s * CAPSEG + (lane - bs)];
    }

    // pipelined float4 gather-sum of matched ff rows (8 flows in flight)
    int fq = lane >> 4, qi = lane & 15;
    const float* ffb = ff + (size_t)b * SS * DD;
    float4 v0 = make_float4(0.f, 0.f, 0.f, 0.f);
    float4 v1 = make_float4(0.f, 0.f, 0.f, 0.f);
    int lim = min(c1, 64);                      // Poisson(16): P(>64) ~ 0
    for (int base = 0; base < lim; base += 8) {
        int w0 = __shfl(bkreg, base + fq, 64);
        int w1 = __shfl(bkreg, base + 4 + fq, 64);
        if (base + fq < lim) {
            float4 xv = ((const float4*)(ffb + (size_t)(w0 & 0xFFFF) * DD))[qi];
            v0.x += xv.x; v0.y += xv.y; v0.z += xv.z; v0.w += xv.w;
        }
        if (base + 4 + fq < lim) {
            float4 xv = ((const float4*)(ffb + (size_t)(w1 & 0xFFFF) * DD))[qi];
            v1.x += xv.x; v1.y += xv.y; v1.z += xv.z; v1.w += xv.w;
        }
    }
    float4 v = make_float4(v0.x + v1.x, v0.y + v1.y, v0.z + v1.z, v0.w + v1.w);
    #pragma unroll
    for (int off = 16; off <= 32; off <<= 1) {  // sum the 4 fq slots
        v.x += __shfl_xor(v.x, off, 64);
        v.y += __shfl_xor(v.y, off, 64);
        v.z += __shfl_xor(v.z, off, 64);
        v.w += __shfl_xor(v.w, off, 64);
    }
    float ssq = (fq == 0) ? (v.x*v.x + v.y*v.y + v.z*v.z + v.w*v.w) : 0.f;
    float nrm = fmaxf(sqrtf(wave_sum(ssq)), 1e-12f);
    float inv = 1.f / nrm;
    if (fq == 0)                                // same-wave DS: ordered
        ((float4*)hs[wave])[qi] = make_float4(v.x*inv, v.y*inv, v.z*inv, v.w*inv);
    float whl = 0.f;
    #pragma unroll 8
    for (int k = 0; k < DD; ++k)                // W row k: coalesced 256 B, hot
        whl = fmaf(hs[wave][k], W[k * DD + lane], whl);
    Wh[(size_t)row * DD + lane] = whl;
    float p1 = wave_sum(whl * a1[lane]);
    float p2 = wave_sum(whl * a2[lane]);
    if (lane == 0) { f1[row] = p1; f2[row] = p2; }

    // neighbor set = union(in-srcs, out-dsts) -> compact ascending list
    if (lane < lim) {
        int s = (bkreg >> 16) & 0x3FF;
        atomicOr(&bm[wave][s >> 5], 1u << (s & 31));
    }
    if (dreg >= 0) {
        int d = dreg & 0x3FF;
        atomicOr(&bm[wave][d >> 5], 1u << (d & 31));
    }
    unsigned int mw_ = (lane < MW) ? bm[wave][lane] : 0u;
    int pc = __popc(mw_);
    int xc = pc;
    #pragma unroll
    for (int off = 1; off < 64; off <<= 1) {
        int y = __shfl_up(xc, off, 64);
        if (lane >= off) xc += y;
    }
    int cnt = __shfl(xc, 63, 64);               // <= 128 = NCAP
    int o = xc - pc;
    int* nrow = nbr + (size_t)row * NCAP;
    unsigned int bits = mw_;
    while (bits) {
        int bi = __ffs(bits) - 1; bits &= bits - 1;
        nrow[o++] = (lane << 5) + bi;
    }
    if (lane == 0) cntn[row] = cnt;
}

// Kernel 3: softmax over precompacted neighbor list + PV + ELU.
// f2 of the whole batch staged in LDS (4 KB, shared by the block's 4 waves,
// all same b) -> no scattered global f2 gathers in either pass.
__global__ __launch_bounds__(256) void attn_kernel(
        const int* __restrict__ cntn, const int* __restrict__ nbr,
        const float* __restrict__ f1, const float* __restrict__ f2,
        const float* __restrict__ Wh, float* __restrict__ out) {
    __shared__ float f2s[NN];                   // 4 KB
    __shared__ int jls[4][NCAP];                // 2 KB
    int t = threadIdx.x, wave = t >> 6, lane = t & 63;
    int row = blockIdx.x * 4 + wave;            // [0, BB*NN)
    int b = row >> 10;
    for (int k = t; k < NN; k += 256) f2s[k] = f2[b * NN + k];
    int fq = lane >> 4, qi = lane & 15;
    int cnt = cntn[row];
    float f1i = f1[row];
    const float* Whb = Wh + (size_t)(b << 10) * DD;
    const int* nrow = nbr + (size_t)row * NCAP;
    for (int k = lane; k < cnt; k += 64) jls[wave][k] = nrow[k];
    __syncthreads();                            // f2s ready (jls same-wave)

    if (cnt > 0) {
        float m = -INFINITY;
        for (int k = lane; k < cnt; k += 64) {
            float e = f1i + f2s[jls[wave][k]];
            e = (e >= 0.f) ? e : 0.2f * e;
            m = fmaxf(m, e);
        }
        m = wave_max(m);
        float4 a0 = make_float4(0.f, 0.f, 0.f, 0.f);
        float4 a1v = make_float4(0.f, 0.f, 0.f, 0.f);
        float psum = 0.f;
        for (int k = fq; k < cnt; k += 8) {
            int j0 = jls[wave][k];
            float e0 = f1i + f2s[j0];
            e0 = (e0 >= 0.f) ? e0 : 0.2f * e0;
            float p0 = __expf(e0 - m);
            float4 w0 = ((const float4*)(Whb + (size_t)j0 * DD))[qi];
            a0.x = fmaf(p0, w0.x, a0.x);
            a0.y = fmaf(p0, w0.y, a0.y);
            a0.z = fmaf(p0, w0.z, a0.z);
            a0.w = fmaf(p0, w0.w, a0.w);
            psum += p0;
            int k1 = k + 4;
            if (k1 < cnt) {
                int j1 = jls[wave][k1];
                float e1 = f1i + f2s[j1];
                e1 = (e1 >= 0.f) ? e1 : 0.2f * e1;
                float p1 = __expf(e1 - m);
                float4 w1 = ((const float4*)(Whb + (size_t)j1 * DD))[qi];
                a1v.x = fmaf(p1, w1.x, a1v.x);
                a1v.y = fmaf(p1, w1.y, a1v.y);
                a1v.z = fmaf(p1, w1.z, a1v.z);
                a1v.w = fmaf(p1, w1.w, a1v.w);
                psum += p1;
            }
        }
        float4 acc = make_float4(a0.x + a1v.x, a0.y + a1v.y,
                                 a0.z + a1v.z, a0.w + a1v.w);
        #pragma unroll
        for (int off = 16; off <= 32; off <<= 1) {
            acc.x += __shfl_xor(acc.x, off, 64);
            acc.y += __shfl_xor(acc.y, off, 64);
            acc.z += __shfl_xor(acc.z, off, 64);
            acc.w += __shfl_xor(acc.w, off, 64);
        }
        float lsum = wave_sum(psum) * (1.f / 16.f);
        if (fq == 0) {
            float invl = 1.f / lsum;
            float4 r;
            r.x = acc.x * invl; r.y = acc.y * invl;
            r.z = acc.z * invl; r.w = acc.w * invl;
            r.x = (r.x > 0.f) ? r.x : expm1f(r.x);
            r.y = (r.y > 0.f) ? r.y : expm1f(r.y);
            r.z = (r.z > 0.f) ? r.z : expm1f(r.z);
            r.w = (r.w > 0.f) ? r.w : expm1f(r.w);
            ((float4*)(out + (size_t)row * DD))[qi] = r;
        }
    } else {
        // isolated node: softmax of uniform NEG_BIG = 1/N over ALL j
        float4 acc = make_float4(0.f, 0.f, 0.f, 0.f);
        for (int k = fq; k < NN; k += 4) {
            float4 w = ((const float4*)(Whb + (size_t)k * DD))[qi];
            acc.x += w.x; acc.y += w.y; acc.z += w.z; acc.w += w.w;
        }
        #pragma unroll
        for (int off = 16; off <= 32; off <<= 1) {
            acc.x += __shfl_xor(acc.x, off, 64);
            acc.y += __shfl_xor(acc.y, off, 64);
            acc.z += __shfl_xor(acc.z, off, 64);
            acc.w += __shfl_xor(acc.w, off, 64);
        }
        if (fq == 0) {
            float4 r;
            r.x = acc.x * (1.f / NN); r.y = acc.y * (1.f / NN);
            r.z = acc.z * (1.f / NN); r.w = acc.w * (1.f / NN);
            r.x = (r.x > 0.f) ? r.x : expm1f(r.x);
            r.y = (r.y > 0.f) ? r.y : expm1f(r.y);
            r.z = (r.z > 0.f) ? r.z : expm1f(r.z);
            r.w = (r.w > 0.f) ? r.w : expm1f(r.w);
            ((float4*)(out + (size_t)row * DD))[qi] = r;
        }
    }
}

extern "C" void kernel_launch(void* const* d_in, const int* in_sizes, int n_in,
                              void* d_out, int out_size, void* d_ws, size_t ws_size,
                              hipStream_t stream) {
    const float* ff      = (const float*)d_in[0];
    const int*   src_ips = (const int*)d_in[1];
    const int*   dst_ips = (const int*)d_in[2];
    // d_in[3] flow_volumes, d_in[4] emb, d_in[5..8] MLP params: adj weights are
    // products of sigmoids => strictly positive => only the >0 mask matters.
    const float* W  = (const float*)d_in[9];
    const float* a1 = (const float*)d_in[10];
    const float* a2 = (const float*)d_in[11];
    float* out = (float*)d_out;

    char* ws = (char*)d_ws;
    unsigned char* cnt8   = (unsigned char*)ws;           // 128 KB
    int*           bkt_d  = (int*)(ws + (1 << 20));       // 6 MB
    unsigned short* bkt_s = (unsigned short*)(ws + (8 << 20)); // 3 MB
    float* Wh   = (float*)(ws + (12 << 20));              // 1 MB
    float* f1   = (float*)(ws + (13 << 20));              // 16 KB
    float* f2   = (float*)(ws + (13 << 20) + (16 << 10)); // 16 KB
    int*   cntn = (int*)(ws + (13 << 20) + (32 << 10));   // 16 KB
    int*   nbr  = (int*)(ws + (14 << 20));                // 2 MB

    build_kernel<<<BB * KSEG, 512, 0, stream>>>(src_ips, dst_ips,
                                                cnt8, bkt_d, bkt_s);
    gather_kernel<<<BB * NN / 4, 256, 0, stream>>>(ff, cnt8, bkt_d, bkt_s,
                                                   W, a1, a2, Wh, f1, f2,
                                                   nbr, cntn);
    attn_kernel<<<BB * NN / 4, 256, 0, stream>>>(cntn, nbr, f1, f2, Wh, out);
}